// Round 5
// baseline (558.703 us; speedup 1.0000x reference)
//
#include <hip/hip_runtime.h>

// Problem constants (match reference)
#define D    128      // embedding dim
#define VSZ  200000   // vocab (emb has VSZ+1 rows, last row = 0)
#define NB   4096     // batch B
#define MM   50       // neighbors
#define DM   256      // 2*D
#define HSZ  512      // H
#define G4   2048     // 4*H
#define PT   2        // emb tiles per proj block

typedef __attribute__((ext_vector_type(8))) short short8;   // 8 bf16 = 4 VGPRs
typedef __attribute__((ext_vector_type(4))) float floatx4;  // MFMA acc

__device__ __forceinline__ float sigf(float x) { return 1.0f / (1.0f + __expf(-x)); }
__device__ __forceinline__ float tanhfast(float x) { return 1.0f - 2.0f / (__expf(2.0f * x) + 1.0f); }
__device__ __forceinline__ unsigned short f2bf(float x) {
    unsigned int u = __float_as_uint(x);
    u += 0x7FFFu + ((u >> 16) & 1u);   // round-to-nearest-even
    return (unsigned short)(u >> 16);
}
__device__ __forceinline__ float bf2f(unsigned short s) {
    return __uint_as_float(((unsigned int)s) << 16);
}

// ---------------------------------------------------------------------------
// Kernel 0: repack gcn_W (128x256 fp32, [d][c]) into bf16 Wb[n][k] for proj.
// ---------------------------------------------------------------------------
__global__ __launch_bounds__(256) void k_wconv(
    const float* __restrict__ gcn_W, unsigned short* __restrict__ Wb)
{
    int i = blockIdx.x * 256 + threadIdx.x;     // 32768 total
    int n = i >> 7, k = i & 127;
    float v = (n < 128) ? gcn_W[n * 256 + k] : gcn_W[(n - 128) * 256 + 128 + k];
    Wb[i] = f2bf(v);
}

// ---------------------------------------------------------------------------
// Kernel 0b: pack Wih (2048x256) and Whh[:, :256] into fragment-linear bf16:
//   chunk idx = (tile*8 + ks)*64 + lane, 8 bf16 per chunk
//   n = tile*16 + (lane&15), k = ks*32 + (lane>>4)*8.  Also gb = bih + bhh.
// ---------------------------------------------------------------------------
__global__ __launch_bounds__(256) void k_pack(
    const float* __restrict__ Wih, const float* __restrict__ Whh,
    const float* __restrict__ bih, const float* __restrict__ bhh,
    unsigned short* __restrict__ Wihp, unsigned short* __restrict__ Whhp,
    float* __restrict__ gb)
{
    int idx = blockIdx.x * 256 + threadIdx.x;
    if (idx < 131072) {
        int ci = idx & 65535;
        int lane = ci & 63, rest = ci >> 6;
        int ks = rest & 7, tile = rest >> 3;
        int n = tile * 16 + (lane & 15), k = ks * 32 + (lane >> 4) * 8;
        const float* src = (idx < 65536) ? (Wih + (size_t)n * 256 + k)
                                         : (Whh + (size_t)n * 512 + k);
        unsigned short* dst = (idx < 65536) ? Wihp : Whhp;
        short8 o;
        #pragma unroll
        for (int j = 0; j < 8; ++j) o[j] = (short)f2bf(src[j]);
        *(short8*)(dst + (size_t)ci * 8) = o;
    } else if (idx < 131072 + 2048) {
        int i = idx - 131072;
        gb[i] = bih[i] + bhh[i];
    }
}

// ---------------------------------------------------------------------------
// Kernel 1: P = emb @ Wcat^T via bf16 MFMA.  2 tiles of 64 rows per block;
// LDS shrunk to 17.4 KB (A-stage reused as 32-row C half-stages) so 4
// blocks/CU fit (round-4: 33.8 KB -> 2.3 blocks/CU, latency-bound at 1.6
// TB/s).  B-fragments reloaded per-ks from L2 to keep VGPR <= 128.
// ---------------------------------------------------------------------------
__global__ __launch_bounds__(256, 4) void k_proj_mfma(
    const float* __restrict__ emb, const unsigned short* __restrict__ Wb,
    const float* __restrict__ gcn_lb, const float* __restrict__ gcn_b,
    unsigned short* __restrict__ P1, unsigned short* __restrict__ P2, int nrows)
{
    __shared__ unsigned short S[64 * 136];   // 17408 B; C half-stage 32*264 fits
    int t = threadIdx.x;
    int lane = t & 63;
    int w = t >> 6;
    int nl = lane & 15, quad = lane >> 4;
    int n0 = w * 64;

    for (int i = 0; i < PT; ++i) {
        int v0 = (blockIdx.x * PT + i) * 64;
        if (v0 >= nrows) break;
        // stage A: 64 rows x 128 cols, fp32 -> bf16, stride 136 shorts
        #pragma unroll
        for (int it = 0; it < 8; ++it) {
            int f = t + 256 * it;          // float4 index, 2048 total
            int r = f >> 5, c4 = f & 31;
            int v = v0 + r;
            float4 ev = make_float4(0.f, 0.f, 0.f, 0.f);
            if (v < nrows) ev = *(const float4*)(emb + (size_t)v * D + c4 * 4);
            ushort4 pk;
            pk.x = f2bf(ev.x); pk.y = f2bf(ev.y); pk.z = f2bf(ev.z); pk.w = f2bf(ev.w);
            *(ushort4*)(S + r * 136 + c4 * 4) = pk;
        }
        __syncthreads();

        floatx4 acc[4][4];
        #pragma unroll
        for (int mt = 0; mt < 4; ++mt)
            #pragma unroll
            for (int nt = 0; nt < 4; ++nt)
                acc[mt][nt] = (floatx4){0.f, 0.f, 0.f, 0.f};

        #pragma unroll
        for (int ks = 0; ks < 4; ++ks) {
            short8 af[4], bf[4];
            #pragma unroll
            for (int mt = 0; mt < 4; ++mt)
                af[mt] = *(const short8*)(S + (mt * 16 + nl) * 136 + ks * 32 + quad * 8);
            #pragma unroll
            for (int nt = 0; nt < 4; ++nt)
                bf[nt] = *(const short8*)(Wb + (size_t)(n0 + nt * 16 + nl) * 128 + ks * 32 + quad * 8);
            #pragma unroll
            for (int mt = 0; mt < 4; ++mt)
                #pragma unroll
                for (int nt = 0; nt < 4; ++nt)
                    acc[mt][nt] = __builtin_amdgcn_mfma_f32_16x16x32_bf16(
                        af[mt], bf[nt], acc[mt][nt], 0, 0, 0);
        }
        __syncthreads();   // A consumed; reuse S as 32-row C half-stage

        #pragma unroll
        for (int h = 0; h < 2; ++h) {
            // write rows h*32..h*32+31 (mt = 2h, 2h+1) to LDS, stride 264
            #pragma unroll
            for (int mh = 0; mh < 2; ++mh) {
                int mt = 2 * h + mh;
                #pragma unroll
                for (int nt = 0; nt < 4; ++nt) {
                    int col = n0 + nt * 16 + nl;
                    float bias = (col < 128) ? (gcn_lb[col] + gcn_b[col]) : 0.f;
                    #pragma unroll
                    for (int reg = 0; reg < 4; ++reg)
                        S[(mh * 16 + quad * 4 + reg) * 264 + col] =
                            f2bf(acc[mt][nt][reg] + bias);
                }
            }
            __syncthreads();
            // coalesced store: 1024 16B chunks
            #pragma unroll
            for (int it = 0; it < 4; ++it) {
                int c = t + 256 * it;
                int row = c >> 5, c8 = c & 31;
                int v = v0 + h * 32 + row;
                if (v < nrows) {
                    int4 val = *(const int4*)(S + row * 264 + c8 * 8);
                    unsigned short* dst = (c8 < 16) ? (P1 + (size_t)v * D + c8 * 8)
                                                    : (P2 + (size_t)v * D + (c8 - 16) * 8);
                    *(int4*)dst = val;
                }
            }
            __syncthreads();
        }
    }
}

// ---------------------------------------------------------------------------
// Kernel 2: neighbor aggregation, both conn tables concurrently.
// One block per (item, side).  16B gathers (8 bf16 per load).
// ---------------------------------------------------------------------------
__global__ __launch_bounds__(256) void k_nbr(
    const int* __restrict__ query, const int* __restrict__ support,
    const int* __restrict__ q_l1, const int* __restrict__ q_l2,
    const int* __restrict__ q_r1, const int* __restrict__ q_r2,
    const int* __restrict__ s_l1, const int* __restrict__ s_l2,
    const int* __restrict__ s_r1, const int* __restrict__ s_r2,
    const unsigned short* __restrict__ P1, const unsigned short* __restrict__ P2,
    const float* __restrict__ emb,
    const float* __restrict__ attn_W, const float* __restrict__ attn_b,
    const float* __restrict__ gate_W, const float* __restrict__ gate_lb,
    const float* __restrict__ gate_b,
    float* __restrict__ qv, unsigned short* __restrict__ qvbf,
    float* __restrict__ sv)
{
    __shared__ unsigned short proj[2 * MM * 136];   // bf16, 27.2 KB
    __shared__ int rel[2 * MM], ent[2 * MM];
    __shared__ float scw[2 * 64];
    __shared__ float scp[2][2][64];
    __shared__ float aw[D], gw[D];
    __shared__ float redg[4];
    __shared__ float gateS[2];
    __shared__ float oth[D];

    int bid = blockIdx.x;
    int item = bid >> 1;
    int side = bid & 1;
    int t = threadIdx.x;

    const int* cA; const int* cB; int selfid; float* outp; bool isq;
    if (item < NB) {
        isq = true;
        cA = (side ? q_r1 : q_l1) + (size_t)item * MM * 2;
        cB = (side ? q_r2 : q_l2) + (size_t)item * MM * 2;
        selfid = query[item * 2 + side];
        outp = qv + (size_t)item * DM + side * D;
    } else {
        isq = false;
        int i2 = item - NB;
        cA = (side ? s_r1 : s_l1) + (size_t)i2 * MM * 2;
        cB = (side ? s_r2 : s_l2) + (size_t)i2 * MM * 2;
        selfid = support[i2 * 2 + side];
        outp = sv + (size_t)i2 * DM + side * D;
    }
    if (t < D) { aw[t] = attn_W[t]; gw[t] = gate_W[t]; }
    if (t < 2 * MM) {
        const int* c = (t < MM) ? cA : cB;
        int m = (t < MM) ? t : t - MM;
        rel[t] = c[m * 2]; ent[t] = c[m * 2 + 1];
    }
    __syncthreads();
    // gather + leakyrelu -> bf16 LDS, 16B loads
    for (int e8 = t; e8 < 2 * MM * 16; e8 += 256) {
        int m = e8 >> 4, d8 = (e8 & 15) * 8;
        short8 a = *(const short8*)(P1 + (size_t)rel[m] * D + d8);
        short8 b = *(const short8*)(P2 + (size_t)ent[m] * D + d8);
        short8 o;
        #pragma unroll
        for (int j = 0; j < 8; ++j) {
            float p = bf2f((unsigned short)a[j]) + bf2f((unsigned short)b[j]);
            p = (p >= 0.f) ? p : 0.01f * p;
            o[j] = (short)f2bf(p);
        }
        *(short8*)(proj + m * 136 + d8) = o;
    }
    __syncthreads();
    // scores: tab = t>>7, half g = (t>>6)&1, m = t&63 (m<50 valid)
    {
        int tab = t >> 7, g = (t >> 6) & 1, m = t & 63;
        float s = 0.f;
        if (m < MM) {
            const unsigned short* pr = proj + (tab * MM + m) * 136 + g * 64;
            #pragma unroll
            for (int i = 0; i < 8; ++i) {
                short8 v8 = *(const short8*)(pr + i * 8);
                #pragma unroll
                for (int j = 0; j < 8; ++j)
                    s += bf2f((unsigned short)v8[j]) * aw[g * 64 + i * 8 + j];
            }
        }
        scp[tab][g][m] = s;
    }
    __syncthreads();
    // softmax per table: wave 0 -> tabA, wave 1 -> tabB
    if (t < 128) {
        int tab = t >> 6, m = t & 63;
        float v = (m < MM) ? (scp[tab][0][m] + scp[tab][1][m] + attn_b[0]) : -1e30f;
        float mx = v;
        #pragma unroll
        for (int o = 32; o > 0; o >>= 1) mx = fmaxf(mx, __shfl_xor(mx, o, 64));
        float ev = (m < MM) ? __expf(v - mx) : 0.f;
        float sm = ev;
        #pragma unroll
        for (int o = 32; o > 0; o >>= 1) sm += __shfl_xor(sm, o, 64);
        if (m < MM) scw[tab * 64 + m] = ev / sm;
    }
    __syncthreads();
    // agg: tab = t>>7, d = t&127
    int tab = t >> 7, d = t & 127;
    float agg = 0.f;
    #pragma unroll 5
    for (int m = 0; m < MM; ++m)
        agg += scw[tab * 64 + m] * bf2f(proj[(tab * MM + m) * 136 + d]);
    // gate scalar per table (2 waves each)
    float gpart = agg * gw[d];
    #pragma unroll
    for (int o = 32; o > 0; o >>= 1) gpart += __shfl_xor(gpart, o, 64);
    if ((t & 63) == 0) redg[t >> 6] = gpart;
    __syncthreads();
    if (t == 0)  gateS[0] = sigf(redg[0] + redg[1] + gate_lb[0] + gate_b[0]);
    if (t == 64) gateS[1] = sigf(redg[2] + redg[3] + gate_lb[0] + gate_b[0]);
    __syncthreads();
    float embd = emb[(size_t)selfid * D + d];
    float val = gateS[tab] * agg + (1.f - gateS[tab]) * embd;
    if (tab == 1) oth[d] = val;
    __syncthreads();
    if (tab == 0) {
        float r = 0.5f * (val + oth[d]);
        outp[d] = r;
        if (isq) qvbf[(size_t)item * DM + side * D + d] = f2bf(r);
    }
}

// ---------------------------------------------------------------------------
// Kernel 3: support vector -> sg (MLP residual + layernorm, ddof=1). 1 block.
// ---------------------------------------------------------------------------
__global__ __launch_bounds__(256) void k_sg(
    const float* __restrict__ sv,
    const float* __restrict__ p1_W, const float* __restrict__ p1_b,
    const float* __restrict__ p2_W, const float* __restrict__ p2_b,
    const float* __restrict__ ln_a, const float* __restrict__ ln_b,
    float* __restrict__ sg)
{
    __shared__ float s[DM];
    __shared__ float hid[2 * DM];
    __shared__ float h[DM];
    __shared__ float red[8];
    int t = threadIdx.x;
    s[t] = sv[t];
    __syncthreads();
    for (int j = t; j < 2 * DM; j += 256) {
        float a = p1_b[j];
        const float* w = p1_W + (size_t)j * DM;
        #pragma unroll 4
        for (int c = 0; c < DM; ++c) a += w[c] * s[c];
        hid[j] = fmaxf(a, 0.f);
    }
    __syncthreads();
    {
        float a = p2_b[t] + s[t];
        const float* w = p2_W + (size_t)t * 2 * DM;
        #pragma unroll 4
        for (int j = 0; j < 2 * DM; ++j) a += w[j] * hid[j];
        h[t] = a;
    }
    __syncthreads();
    float x = h[t];
    float sm = x;
    #pragma unroll
    for (int o = 32; o > 0; o >>= 1) sm += __shfl_xor(sm, o, 64);
    if ((t & 63) == 0) red[t >> 6] = sm;
    __syncthreads();
    float mu = (red[0] + red[1] + red[2] + red[3]) * (1.0f / 256.0f);
    float dv = x - mu;
    float sq = dv * dv;
    #pragma unroll
    for (int o = 32; o > 0; o >>= 1) sq += __shfl_xor(sq, o, 64);
    if ((t & 63) == 0) red[4 + (t >> 6)] = sq;
    __syncthreads();
    float var = (red[4] + red[5] + red[6] + red[7]) * (1.0f / 255.0f);  // ddof=1
    float sig = sqrtf(var);
    sg[t] = dv / (sig + 0.001f) * ln_a[t] + ln_b[t];
}

// ---------------------------------------------------------------------------
// Kernel 4: sgW[k] = sum_j sg[j] * Whh[k, 256+j]  (constant over batch)
// ---------------------------------------------------------------------------
__global__ __launch_bounds__(256) void k_sgwhh(
    const float* __restrict__ sg, const float* __restrict__ Whh,
    float* __restrict__ sgW)
{
    __shared__ float s[DM];
    int t = threadIdx.x;
    s[t] = sg[t];
    __syncthreads();
    int k = blockIdx.x * 256 + t;
    const float* w = Whh + (size_t)k * HSZ + DM;
    float a = 0.f;
    #pragma unroll 4
    for (int j = 0; j < DM; ++j) a += w[j] * s[j];
    sgW[k] = a;
}

// ---------------------------------------------------------------------------
// Kernel 5: zero d_out (re-poisoned before every timed launch; final LSTM
// step accumulates into it with atomics).
// ---------------------------------------------------------------------------
__global__ __launch_bounds__(256) void k_zero(float* __restrict__ p)
{
    p[blockIdx.x * 256 + threadIdx.x] = 0.f;
}

// ---------------------------------------------------------------------------
// Kernel 6: fused LSTM step via MFMA.  Block = 32 batch rows; wave w owns ONE
// column tile T = blockIdx.y*4 + w (grid y=8 for modes 0/1; y=4 for mode 2)
// plus its gate tiles T+32g -> all four gates of col k=T*16+nl in-wave.
// g0 and C are stored in MFMA-FRAGMENT layout (producer and consumer use the
// same lane mapping) -> fully coalesced 8B/16B per-lane I/O instead of the
// round-4 2B column-strided scatter.
//   g0f idx: (((bx*128 + g*32 + T)*2 + mt)*64 + lane) * 4 ushorts (r=0..3)
//   Cf  idx: (((bx*32 + T)*2 + mt)*64 + lane)            float4   (r=0..3)
//   mode 0: A = qv(bf16), B = Wihp. g = A@B + gb; store g0f, Cf, hq.
//   mode 1: A = hq,       B = Whhp. g = A@B + g0f + sgW; Cf; hq.
//   mode 2: like 1, no stores; atomicAdd dot(h, sg) into out.
// ---------------------------------------------------------------------------
__global__ __launch_bounds__(256, 4) void k_lstm(
    const float* __restrict__ qv, const unsigned short* __restrict__ Ain,
    const unsigned short* __restrict__ Bp,
    const float* __restrict__ gb, const float* __restrict__ sgW,
    const unsigned short* __restrict__ g0i, unsigned short* __restrict__ g0o,
    float4* __restrict__ Cf, unsigned short* __restrict__ hqo,
    const float* __restrict__ sg, float* __restrict__ out, int mode)
{
    int t = threadIdx.x;
    int lane = t & 63, w = t >> 6;
    int nl = lane & 15, quad = lane >> 4;
    int bx = blockIdx.x;
    int b0 = bx * 32;
    int T = blockIdx.y * 4 + w;

    floatx4 acc[2][4];
    #pragma unroll
    for (int mt = 0; mt < 2; ++mt)
        #pragma unroll
        for (int g = 0; g < 4; ++g) acc[mt][g] = (floatx4){0.f, 0.f, 0.f, 0.f};

    for (int ks = 0; ks < 8; ++ks) {
        short8 af0 = *(const short8*)(Ain + (size_t)(b0 + nl) * DM + ks * 32 + quad * 8);
        short8 af1 = *(const short8*)(Ain + (size_t)(b0 + 16 + nl) * DM + ks * 32 + quad * 8);
        #pragma unroll
        for (int g = 0; g < 4; ++g) {
            short8 bfr = *(const short8*)(Bp + ((size_t)((T + 32 * g) * 8 + ks) * 64 + lane) * 8);
            acc[0][g] = __builtin_amdgcn_mfma_f32_16x16x32_bf16(af0, bfr, acc[0][g], 0, 0, 0);
            acc[1][g] = __builtin_amdgcn_mfma_f32_16x16x32_bf16(af1, bfr, acc[1][g], 0, 0, 0);
        }
    }

    int coli = T * 16 + nl;
    float preg[2][4] = {{0.f, 0.f, 0.f, 0.f}, {0.f, 0.f, 0.f, 0.f}};
    #pragma unroll
    for (int mt = 0; mt < 2; ++mt) {
        size_t cfi = (((size_t)bx * 32 + T) * 2 + mt) * 64 + lane;
        if (mode == 0) {
            float bi = gb[coli], bff = gb[coli + 512];
            float bg = gb[coli + 1024], bo = gb[coli + 1536];
            float4 cn4; ushort4 pk[4];
            #pragma unroll
            for (int r = 0; r < 4; ++r) {
                float gi_ = acc[mt][0][r] + bi;
                float gf_ = acc[mt][1][r] + bff;
                float gg_ = acc[mt][2][r] + bg;
                float go_ = acc[mt][3][r] + bo;
                pk[0].x = 0; // placeholder, filled below via arrays
                float cn = sigf(gi_) * tanhfast(gg_);
                (&cn4.x)[r] = cn;
                // pack per-gate bf16 of this r
                ((unsigned short*)&pk[0])[r] = f2bf(gi_);
                ((unsigned short*)&pk[1])[r] = f2bf(gf_);
                ((unsigned short*)&pk[2])[r] = f2bf(gg_);
                ((unsigned short*)&pk[3])[r] = f2bf(go_);
                if (T < 16) {
                    int b = b0 + mt * 16 + quad * 4 + r;
                    float h = qv[(size_t)b * DM + coli] + sigf(go_) * tanhfast(cn);
                    hqo[(size_t)b * DM + coli] = f2bf(h);
                }
            }
            #pragma unroll
            for (int g = 0; g < 4; ++g) {
                size_t gfi = ((((size_t)bx * 128 + g * 32 + T) * 2 + mt) * 64 + lane) * 4;
                *(ushort4*)(g0o + gfi) = pk[g];
            }
            Cf[cfi] = cn4;
        } else {
            float si = sgW[coli], sf = sgW[coli + 512];
            float sgg = sgW[coli + 1024], so = sgW[coli + 1536];
            ushort4 gld[4];
            #pragma unroll
            for (int g = 0; g < 4; ++g) {
                size_t gfi = ((((size_t)bx * 128 + g * 32 + T) * 2 + mt) * 64 + lane) * 4;
                gld[g] = *(const ushort4*)(g0i + gfi);
            }
            float4 cold = Cf[cfi];
            float4 cn4;
            #pragma unroll
            for (int r = 0; r < 4; ++r) {
                float gi_ = acc[mt][0][r] + si  + bf2f(((unsigned short*)&gld[0])[r]);
                float gf_ = acc[mt][1][r] + sf  + bf2f(((unsigned short*)&gld[1])[r]);
                float gg_ = acc[mt][2][r] + sgg + bf2f(((unsigned short*)&gld[2])[r]);
                float go_ = acc[mt][3][r] + so  + bf2f(((unsigned short*)&gld[3])[r]);
                float cn = sigf(gf_) * (&cold.x)[r] + sigf(gi_) * tanhfast(gg_);
                (&cn4.x)[r] = cn;
                if (T < 16) {
                    int b = b0 + mt * 16 + quad * 4 + r;
                    float h = qv[(size_t)b * DM + coli] + sigf(go_) * tanhfast(cn);
                    if (mode == 1) hqo[(size_t)b * DM + coli] = f2bf(h);
                    else           preg[mt][r] += h * sg[coli];
                }
            }
            if (mode == 1) Cf[cfi] = cn4;
        }
    }

    if (mode == 2) {
        #pragma unroll
        for (int mt = 0; mt < 2; ++mt)
            #pragma unroll
            for (int r = 0; r < 4; ++r) {
                float p = preg[mt][r];
                p += __shfl_xor(p, 1, 64);
                p += __shfl_xor(p, 2, 64);
                p += __shfl_xor(p, 4, 64);
                p += __shfl_xor(p, 8, 64);
                if (nl == 0)
                    atomicAdd(out + b0 + mt * 16 + quad * 4 + r, p);
            }
    }
}

// ---------------------------------------------------------------------------
extern "C" void kernel_launch(void* const* d_in, const int* in_sizes, int n_in,
                              void* d_out, int out_size, void* d_ws, size_t ws_size,
                              hipStream_t stream) {
    const int* query   = (const int*)d_in[0];
    const int* support = (const int*)d_in[1];
    const int* q_l1 = (const int*)d_in[2];
    const int* q_l2 = (const int*)d_in[3];
    const int* q_r1 = (const int*)d_in[5];
    const int* q_r2 = (const int*)d_in[6];
    const int* s_l1 = (const int*)d_in[8];
    const int* s_l2 = (const int*)d_in[9];
    const int* s_r1 = (const int*)d_in[11];
    const int* s_r2 = (const int*)d_in[12];
    const float* emb    = (const float*)d_in[14];
    const float* gcn_W  = (const float*)d_in[15];
    const float* gcn_lb = (const float*)d_in[16];
    const float* gcn_b  = (const float*)d_in[17];
    const float* attn_W = (const float*)d_in[18];
    const float* attn_b = (const float*)d_in[19];
    const float* gate_W = (const float*)d_in[20];
    const float* gate_lb = (const float*)d_in[21];
    const float* gate_b  = (const float*)d_in[22];
    const float* p1_W = (const float*)d_in[23];
    const float* p1_b = (const float*)d_in[24];
    const float* p2_W = (const float*)d_in[25];
    const float* p2_b = (const float*)d_in[26];
    const float* ln_a = (const float*)d_in[27];
    const float* ln_b = (const float*)d_in[28];
    const float* Wih  = (const float*)d_in[29];
    const float* Whh  = (const float*)d_in[30];
    const float* bih  = (const float*)d_in[31];
    const float* bhh  = (const float*)d_in[32];

    // workspace layout: bf16 buffers first, then fp32 (16B-aligned blocks)
    unsigned short* P1   = (unsigned short*)d_ws;               // (V+1)*128
    unsigned short* P2   = P1 + (size_t)(VSZ + 1) * D;
    unsigned short* Wb   = P2 + (size_t)(VSZ + 1) * D;          // 256*128
    unsigned short* Wihp = Wb + 256 * 128;                      // 65536*8
    unsigned short* Whhp = Wihp + (size_t)65536 * 8;            // 65536*8
    unsigned short* g0b  = Whhp + (size_t)65536 * 8;            // NB*2048 (frag)
    unsigned short* hqb  = g0b + (size_t)NB * G4;               // NB*256
    unsigned short* qvbf = hqb + (size_t)NB * DM;               // NB*256
    float* fws = (float*)(qvbf + (size_t)NB * DM);
    float* gbv = fws;  fws += G4;
    float* qvb = fws;  fws += (size_t)NB * DM;                  // 4 MB
    float* svb = fws;  fws += DM;
    float* sgb = fws;  fws += DM;
    float* sgW = fws;  fws += G4 + 4;   // keep next block 16B-aligned
    float4* Cf = (float4*)fws;  fws += (size_t)NB * HSZ;        // 8 MB (frag)
    (void)in_sizes; (void)n_in; (void)out_size; (void)ws_size;

    k_wconv<<<128, 256, 0, stream>>>(gcn_W, Wb);
    k_pack<<<(131072 + 2048) / 256, 256, 0, stream>>>(
        Wih, Whh, bih, bhh, Wihp, Whhp, gbv);
    k_proj_mfma<<<(VSZ + 1 + 64 * PT - 1) / (64 * PT), 256, 0, stream>>>(
        emb, Wb, gcn_lb, gcn_b, P1, P2, VSZ + 1);
    k_nbr<<<2 * (NB + 1), 256, 0, stream>>>(
        query, support, q_l1, q_l2, q_r1, q_r2, s_l1, s_l2, s_r1, s_r2,
        P1, P2, emb, attn_W, attn_b, gate_W, gate_lb, gate_b, qvb, qvbf, svb);
    k_sg<<<1, 256, 0, stream>>>(svb, p1_W, p1_b, p2_W, p2_b, ln_a, ln_b, sgb);
    k_sgwhh<<<G4 / 256, 256, 0, stream>>>(sgb, Whh, sgW);
    // step 1 (h_r = 0): A = qv bf16, B = Wih; store g0 frags, Cf, hq
    k_lstm<<<dim3(NB / 32, 8), 256, 0, stream>>>(
        qvb, qvbf, Wihp, gbv, sgW, g0b, g0b, Cf, hqb, sgb, (float*)d_out, 0);
    // steps 2,3: A = hq, B = Whh[:, :256]; g = g0 + sgW + A@B
    k_lstm<<<dim3(NB / 32, 8), 256, 0, stream>>>(
        qvb, hqb, Whhp, gbv, sgW, g0b, g0b, Cf, hqb, sgb, (float*)d_out, 1);
    k_lstm<<<dim3(NB / 32, 8), 256, 0, stream>>>(
        qvb, hqb, Whhp, gbv, sgW, g0b, g0b, Cf, hqb, sgb, (float*)d_out, 1);
    // step 4: only cols < 256 matter -> y < 4; atomic dot into zeroed out
    k_zero<<<NB / 256, 256, 0, stream>>>((float*)d_out);
    k_lstm<<<dim3(NB / 32, 4), 256, 0, stream>>>(
        qvb, hqb, Whhp, gbv, sgW, g0b, g0b, Cf, hqb, sgb, (float*)d_out, 2);
}

// Round 6
// 485.217 us; speedup vs baseline: 1.1514x; 1.1514x over previous
//
#include <hip/hip_runtime.h>

// Problem constants (match reference)
#define D    128      // embedding dim
#define VSZ  200000   // vocab (emb has VSZ+1 rows, last row = 0)
#define NB   4096     // batch B
#define MM   50       // neighbors
#define DM   256      // 2*D
#define HSZ  512      // H
#define G4   2048     // 4*H

typedef __attribute__((ext_vector_type(8))) short short8;   // 8 bf16 = 4 VGPRs
typedef __attribute__((ext_vector_type(4))) float floatx4;  // MFMA acc

__device__ __forceinline__ float sigf(float x) { return 1.0f / (1.0f + __expf(-x)); }
__device__ __forceinline__ float tanhfast(float x) { return 1.0f - 2.0f / (__expf(2.0f * x) + 1.0f); }
__device__ __forceinline__ unsigned short f2bf(float x) {
    unsigned int u = __float_as_uint(x);
    u += 0x7FFFu + ((u >> 16) & 1u);   // round-to-nearest-even
    return (unsigned short)(u >> 16);
}
__device__ __forceinline__ float bf2f(unsigned short s) {
    return __uint_as_float(((unsigned int)s) << 16);
}

// ---------------------------------------------------------------------------
// Kernel 0: repack gcn_W (128x256 fp32, [d][c]) into bf16 Wb[n][k] for proj.
// ---------------------------------------------------------------------------
__global__ __launch_bounds__(256) void k_wconv(
    const float* __restrict__ gcn_W, unsigned short* __restrict__ Wb)
{
    int i = blockIdx.x * 256 + threadIdx.x;     // 32768 total
    int n = i >> 7, k = i & 127;
    float v = (n < 128) ? gcn_W[n * 256 + k] : gcn_W[(n - 128) * 256 + 128 + k];
    Wb[i] = f2bf(v);
}

// ---------------------------------------------------------------------------
// Kernel 0b: pack Wih (2048x256) and Whh[:, :256] into fragment-linear bf16:
//   chunk idx = (tile*8 + ks)*64 + lane, 8 bf16 per chunk
//   n = tile*16 + (lane&15), k = ks*32 + (lane>>4)*8.  Also gb = bih + bhh.
// ---------------------------------------------------------------------------
__global__ __launch_bounds__(256) void k_pack(
    const float* __restrict__ Wih, const float* __restrict__ Whh,
    const float* __restrict__ bih, const float* __restrict__ bhh,
    unsigned short* __restrict__ Wihp, unsigned short* __restrict__ Whhp,
    float* __restrict__ gb)
{
    int idx = blockIdx.x * 256 + threadIdx.x;
    if (idx < 131072) {
        int ci = idx & 65535;
        int lane = ci & 63, rest = ci >> 6;
        int ks = rest & 7, tile = rest >> 3;
        int n = tile * 16 + (lane & 15), k = ks * 32 + (lane >> 4) * 8;
        const float* src = (idx < 65536) ? (Wih + (size_t)n * 256 + k)
                                         : (Whh + (size_t)n * 512 + k);
        unsigned short* dst = (idx < 65536) ? Wihp : Whhp;
        short8 o;
        #pragma unroll
        for (int j = 0; j < 8; ++j) o[j] = (short)f2bf(src[j]);
        *(short8*)(dst + (size_t)ci * 8) = o;
    } else if (idx < 131072 + 2048) {
        int i = idx - 131072;
        gb[i] = bih[i] + bhh[i];
    }
}

// ---------------------------------------------------------------------------
// Kernel 1: P = emb @ Wcat^T via bf16 MFMA.  Block: 64 emb rows x 256 cols.
// Round-4 body (plain launch_bounds, hoisted B-frags, VGPR ~84, NO spill —
// round-5's (256,4) clamp spilled acc to scratch: WRITE 100->236 MB) with the
// epilogue staged in two 32-row halves so LDS stays at 17.4 KB.
// ---------------------------------------------------------------------------
__global__ __launch_bounds__(256) void k_proj_mfma(
    const float* __restrict__ emb, const unsigned short* __restrict__ Wb,
    const float* __restrict__ gcn_lb, const float* __restrict__ gcn_b,
    unsigned short* __restrict__ P1, unsigned short* __restrict__ P2, int nrows)
{
    __shared__ unsigned short S[64 * 136];   // 17408 B; C half-stage 32*264 fits
    int t = threadIdx.x;
    int v0 = blockIdx.x * 64;
    // stage A: 64 rows x 128 cols, fp32 -> bf16, stride 136 shorts
    #pragma unroll
    for (int it = 0; it < 8; ++it) {
        int f = t + 256 * it;          // float4 index, 2048 total
        int r = f >> 5, c4 = f & 31;
        int v = v0 + r;
        float4 ev = make_float4(0.f, 0.f, 0.f, 0.f);
        if (v < nrows) ev = *(const float4*)(emb + (size_t)v * D + c4 * 4);
        ushort4 pk;
        pk.x = f2bf(ev.x); pk.y = f2bf(ev.y); pk.z = f2bf(ev.z); pk.w = f2bf(ev.w);
        *(ushort4*)(S + r * 136 + c4 * 4) = pk;
    }
    __syncthreads();

    int lane = t & 63;
    int w = t >> 6;
    int nl = lane & 15, quad = lane >> 4;
    int n0 = w * 64;

    short8 bf[4][4];
    #pragma unroll
    for (int nt = 0; nt < 4; ++nt)
        #pragma unroll
        for (int ks = 0; ks < 4; ++ks)
            bf[nt][ks] = *(const short8*)(Wb + (size_t)(n0 + nt * 16 + nl) * 128 + ks * 32 + quad * 8);

    floatx4 acc[4][4];
    #pragma unroll
    for (int mt = 0; mt < 4; ++mt)
        #pragma unroll
        for (int nt = 0; nt < 4; ++nt)
            acc[mt][nt] = (floatx4){0.f, 0.f, 0.f, 0.f};

    #pragma unroll
    for (int ks = 0; ks < 4; ++ks) {
        short8 af[4];
        #pragma unroll
        for (int mt = 0; mt < 4; ++mt)
            af[mt] = *(const short8*)(S + (mt * 16 + nl) * 136 + ks * 32 + quad * 8);
        #pragma unroll
        for (int mt = 0; mt < 4; ++mt)
            #pragma unroll
            for (int nt = 0; nt < 4; ++nt)
                acc[mt][nt] = __builtin_amdgcn_mfma_f32_16x16x32_bf16(
                    af[mt], bf[nt][ks], acc[mt][nt], 0, 0, 0);
    }

    __syncthreads();   // A consumed; reuse S as 32-row C half-stage
    #pragma unroll
    for (int h = 0; h < 2; ++h) {
        #pragma unroll
        for (int mh = 0; mh < 2; ++mh) {
            int mt = 2 * h + mh;
            #pragma unroll
            for (int nt = 0; nt < 4; ++nt) {
                int col = n0 + nt * 16 + nl;
                float bias = (col < 128) ? (gcn_lb[col] + gcn_b[col]) : 0.f;
                #pragma unroll
                for (int reg = 0; reg < 4; ++reg)
                    S[(mh * 16 + quad * 4 + reg) * 264 + col] =
                        f2bf(acc[mt][nt][reg] + bias);
            }
        }
        __syncthreads();
        // coalesced store: 1024 16B chunks for this 32-row half
        #pragma unroll
        for (int it = 0; it < 4; ++it) {
            int c = t + 256 * it;
            int row = c >> 5, c8 = c & 31;
            int v = v0 + h * 32 + row;
            if (v < nrows) {
                int4 val = *(const int4*)(S + row * 264 + c8 * 8);
                unsigned short* dst = (c8 < 16) ? (P1 + (size_t)v * D + c8 * 8)
                                                : (P2 + (size_t)v * D + (c8 - 16) * 8);
                *(int4*)dst = val;
            }
        }
        __syncthreads();
    }
}

// ---------------------------------------------------------------------------
// Kernel 2: neighbor aggregation, both conn tables concurrently.
// One block per (item, side).  16B gathers (8 bf16 per load).
// ---------------------------------------------------------------------------
__global__ __launch_bounds__(256) void k_nbr(
    const int* __restrict__ query, const int* __restrict__ support,
    const int* __restrict__ q_l1, const int* __restrict__ q_l2,
    const int* __restrict__ q_r1, const int* __restrict__ q_r2,
    const int* __restrict__ s_l1, const int* __restrict__ s_l2,
    const int* __restrict__ s_r1, const int* __restrict__ s_r2,
    const unsigned short* __restrict__ P1, const unsigned short* __restrict__ P2,
    const float* __restrict__ emb,
    const float* __restrict__ attn_W, const float* __restrict__ attn_b,
    const float* __restrict__ gate_W, const float* __restrict__ gate_lb,
    const float* __restrict__ gate_b,
    float* __restrict__ qv, unsigned short* __restrict__ qvbf,
    float* __restrict__ sv)
{
    __shared__ unsigned short proj[2 * MM * 136];   // bf16, 27.2 KB
    __shared__ int rel[2 * MM], ent[2 * MM];
    __shared__ float scw[2 * 64];
    __shared__ float scp[2][2][64];
    __shared__ float aw[D], gw[D];
    __shared__ float redg[4];
    __shared__ float gateS[2];
    __shared__ float oth[D];

    int bid = blockIdx.x;
    int item = bid >> 1;
    int side = bid & 1;
    int t = threadIdx.x;

    const int* cA; const int* cB; int selfid; float* outp; bool isq;
    if (item < NB) {
        isq = true;
        cA = (side ? q_r1 : q_l1) + (size_t)item * MM * 2;
        cB = (side ? q_r2 : q_l2) + (size_t)item * MM * 2;
        selfid = query[item * 2 + side];
        outp = qv + (size_t)item * DM + side * D;
    } else {
        isq = false;
        int i2 = item - NB;
        cA = (side ? s_r1 : s_l1) + (size_t)i2 * MM * 2;
        cB = (side ? s_r2 : s_l2) + (size_t)i2 * MM * 2;
        selfid = support[i2 * 2 + side];
        outp = sv + (size_t)i2 * DM + side * D;
    }
    if (t < D) { aw[t] = attn_W[t]; gw[t] = gate_W[t]; }
    if (t < 2 * MM) {
        const int* c = (t < MM) ? cA : cB;
        int m = (t < MM) ? t : t - MM;
        rel[t] = c[m * 2]; ent[t] = c[m * 2 + 1];
    }
    __syncthreads();
    // gather + leakyrelu -> bf16 LDS, 16B loads
    for (int e8 = t; e8 < 2 * MM * 16; e8 += 256) {
        int m = e8 >> 4, d8 = (e8 & 15) * 8;
        short8 a = *(const short8*)(P1 + (size_t)rel[m] * D + d8);
        short8 b = *(const short8*)(P2 + (size_t)ent[m] * D + d8);
        short8 o;
        #pragma unroll
        for (int j = 0; j < 8; ++j) {
            float p = bf2f((unsigned short)a[j]) + bf2f((unsigned short)b[j]);
            p = (p >= 0.f) ? p : 0.01f * p;
            o[j] = (short)f2bf(p);
        }
        *(short8*)(proj + m * 136 + d8) = o;
    }
    __syncthreads();
    // scores: tab = t>>7, half g = (t>>6)&1, m = t&63 (m<50 valid)
    {
        int tab = t >> 7, g = (t >> 6) & 1, m = t & 63;
        float s = 0.f;
        if (m < MM) {
            const unsigned short* pr = proj + (tab * MM + m) * 136 + g * 64;
            #pragma unroll
            for (int i = 0; i < 8; ++i) {
                short8 v8 = *(const short8*)(pr + i * 8);
                #pragma unroll
                for (int j = 0; j < 8; ++j)
                    s += bf2f((unsigned short)v8[j]) * aw[g * 64 + i * 8 + j];
            }
        }
        scp[tab][g][m] = s;
    }
    __syncthreads();
    // softmax per table: wave 0 -> tabA, wave 1 -> tabB
    if (t < 128) {
        int tab = t >> 6, m = t & 63;
        float v = (m < MM) ? (scp[tab][0][m] + scp[tab][1][m] + attn_b[0]) : -1e30f;
        float mx = v;
        #pragma unroll
        for (int o = 32; o > 0; o >>= 1) mx = fmaxf(mx, __shfl_xor(mx, o, 64));
        float ev = (m < MM) ? __expf(v - mx) : 0.f;
        float sm = ev;
        #pragma unroll
        for (int o = 32; o > 0; o >>= 1) sm += __shfl_xor(sm, o, 64);
        if (m < MM) scw[tab * 64 + m] = ev / sm;
    }
    __syncthreads();
    // agg: tab = t>>7, d = t&127
    int tab = t >> 7, d = t & 127;
    float agg = 0.f;
    #pragma unroll 5
    for (int m = 0; m < MM; ++m)
        agg += scw[tab * 64 + m] * bf2f(proj[(tab * MM + m) * 136 + d]);
    // gate scalar per table (2 waves each)
    float gpart = agg * gw[d];
    #pragma unroll
    for (int o = 32; o > 0; o >>= 1) gpart += __shfl_xor(gpart, o, 64);
    if ((t & 63) == 0) redg[t >> 6] = gpart;
    __syncthreads();
    if (t == 0)  gateS[0] = sigf(redg[0] + redg[1] + gate_lb[0] + gate_b[0]);
    if (t == 64) gateS[1] = sigf(redg[2] + redg[3] + gate_lb[0] + gate_b[0]);
    __syncthreads();
    float embd = emb[(size_t)selfid * D + d];
    float val = gateS[tab] * agg + (1.f - gateS[tab]) * embd;
    if (tab == 1) oth[d] = val;
    __syncthreads();
    if (tab == 0) {
        float r = 0.5f * (val + oth[d]);
        outp[d] = r;
        if (isq) qvbf[(size_t)item * DM + side * D + d] = f2bf(r);
    }
}

// ---------------------------------------------------------------------------
// Kernel 3: support vector -> sg (MLP residual + layernorm, ddof=1). 1 block.
// ---------------------------------------------------------------------------
__global__ __launch_bounds__(256) void k_sg(
    const float* __restrict__ sv,
    const float* __restrict__ p1_W, const float* __restrict__ p1_b,
    const float* __restrict__ p2_W, const float* __restrict__ p2_b,
    const float* __restrict__ ln_a, const float* __restrict__ ln_b,
    float* __restrict__ sg)
{
    __shared__ float s[DM];
    __shared__ float hid[2 * DM];
    __shared__ float h[DM];
    __shared__ float red[8];
    int t = threadIdx.x;
    s[t] = sv[t];
    __syncthreads();
    for (int j = t; j < 2 * DM; j += 256) {
        float a = p1_b[j];
        const float* w = p1_W + (size_t)j * DM;
        #pragma unroll 4
        for (int c = 0; c < DM; ++c) a += w[c] * s[c];
        hid[j] = fmaxf(a, 0.f);
    }
    __syncthreads();
    {
        float a = p2_b[t] + s[t];
        const float* w = p2_W + (size_t)t * 2 * DM;
        #pragma unroll 4
        for (int j = 0; j < 2 * DM; ++j) a += w[j] * hid[j];
        h[t] = a;
    }
    __syncthreads();
    float x = h[t];
    float sm = x;
    #pragma unroll
    for (int o = 32; o > 0; o >>= 1) sm += __shfl_xor(sm, o, 64);
    if ((t & 63) == 0) red[t >> 6] = sm;
    __syncthreads();
    float mu = (red[0] + red[1] + red[2] + red[3]) * (1.0f / 256.0f);
    float dv = x - mu;
    float sq = dv * dv;
    #pragma unroll
    for (int o = 32; o > 0; o >>= 1) sq += __shfl_xor(sq, o, 64);
    if ((t & 63) == 0) red[4 + (t >> 6)] = sq;
    __syncthreads();
    float var = (red[4] + red[5] + red[6] + red[7]) * (1.0f / 255.0f);  // ddof=1
    float sig = sqrtf(var);
    sg[t] = dv / (sig + 0.001f) * ln_a[t] + ln_b[t];
}

// ---------------------------------------------------------------------------
// Kernel 4: sgW[k] = sum_j sg[j] * Whh[k, 256+j]  (constant over batch)
// ---------------------------------------------------------------------------
__global__ __launch_bounds__(256) void k_sgwhh(
    const float* __restrict__ sg, const float* __restrict__ Whh,
    float* __restrict__ sgW)
{
    __shared__ float s[DM];
    int t = threadIdx.x;
    s[t] = sg[t];
    __syncthreads();
    int k = blockIdx.x * 256 + t;
    const float* w = Whh + (size_t)k * HSZ + DM;
    float a = 0.f;
    #pragma unroll 4
    for (int j = 0; j < DM; ++j) a += w[j] * s[j];
    sgW[k] = a;
}

// ---------------------------------------------------------------------------
// Kernel 5: zero d_out (re-poisoned before every timed launch; final LSTM
// step accumulates into it with atomics).
// ---------------------------------------------------------------------------
__global__ __launch_bounds__(256) void k_zero(float* __restrict__ p)
{
    p[blockIdx.x * 256 + threadIdx.x] = 0.f;
}

// ---------------------------------------------------------------------------
// Kernel 6: fused LSTM step via MFMA.  Block = 32 batch rows; wave w owns ONE
// column tile T = blockIdx.y*4 + w (grid y=8 for modes 0/1; y=4 for mode 2)
// plus its gate tiles T+32g -> all four gates of col k=T*16+nl in-wave.
// g0 and C live in MFMA-fragment layout (coalesced per-lane I/O).
// hq uses PING-PONG buffers across launches: round-5 wrote hq in place,
// racing co-resident blocks of the same launch that still read it as A.
//   mode 0: A = qv(bf16), B = Wihp. g = A@B + gb; store g0f, Cf, hq->hqo.
//   mode 1: A = Ain,      B = Whhp. g = A@B + g0f + sgW; Cf; hq->hqo.
//   mode 2: like 1, no stores; atomicAdd dot(h, sg) into out.
// ---------------------------------------------------------------------------
__global__ __launch_bounds__(256, 4) void k_lstm(
    const float* __restrict__ qv, const unsigned short* __restrict__ Ain,
    const unsigned short* __restrict__ Bp,
    const float* __restrict__ gb, const float* __restrict__ sgW,
    const unsigned short* __restrict__ g0i, unsigned short* __restrict__ g0o,
    float4* __restrict__ Cf, unsigned short* __restrict__ hqo,
    const float* __restrict__ sg, float* __restrict__ out, int mode)
{
    int t = threadIdx.x;
    int lane = t & 63, w = t >> 6;
    int nl = lane & 15, quad = lane >> 4;
    int bx = blockIdx.x;
    int b0 = bx * 32;
    int T = blockIdx.y * 4 + w;

    floatx4 acc[2][4];
    #pragma unroll
    for (int mt = 0; mt < 2; ++mt)
        #pragma unroll
        for (int g = 0; g < 4; ++g) acc[mt][g] = (floatx4){0.f, 0.f, 0.f, 0.f};

    for (int ks = 0; ks < 8; ++ks) {
        short8 af0 = *(const short8*)(Ain + (size_t)(b0 + nl) * DM + ks * 32 + quad * 8);
        short8 af1 = *(const short8*)(Ain + (size_t)(b0 + 16 + nl) * DM + ks * 32 + quad * 8);
        #pragma unroll
        for (int g = 0; g < 4; ++g) {
            short8 bfr = *(const short8*)(Bp + ((size_t)((T + 32 * g) * 8 + ks) * 64 + lane) * 8);
            acc[0][g] = __builtin_amdgcn_mfma_f32_16x16x32_bf16(af0, bfr, acc[0][g], 0, 0, 0);
            acc[1][g] = __builtin_amdgcn_mfma_f32_16x16x32_bf16(af1, bfr, acc[1][g], 0, 0, 0);
        }
    }

    int coli = T * 16 + nl;
    float preg[2][4] = {{0.f, 0.f, 0.f, 0.f}, {0.f, 0.f, 0.f, 0.f}};
    #pragma unroll
    for (int mt = 0; mt < 2; ++mt) {
        size_t cfi = (((size_t)bx * 32 + T) * 2 + mt) * 64 + lane;
        if (mode == 0) {
            float bi = gb[coli], bff = gb[coli + 512];
            float bg = gb[coli + 1024], bo = gb[coli + 1536];
            float4 cn4; ushort4 pk[4];
            #pragma unroll
            for (int r = 0; r < 4; ++r) {
                float gi_ = acc[mt][0][r] + bi;
                float gf_ = acc[mt][1][r] + bff;
                float gg_ = acc[mt][2][r] + bg;
                float go_ = acc[mt][3][r] + bo;
                float cn = sigf(gi_) * tanhfast(gg_);
                (&cn4.x)[r] = cn;
                ((unsigned short*)&pk[0])[r] = f2bf(gi_);
                ((unsigned short*)&pk[1])[r] = f2bf(gf_);
                ((unsigned short*)&pk[2])[r] = f2bf(gg_);
                ((unsigned short*)&pk[3])[r] = f2bf(go_);
                if (T < 16) {
                    int b = b0 + mt * 16 + quad * 4 + r;
                    float h = qv[(size_t)b * DM + coli] + sigf(go_) * tanhfast(cn);
                    hqo[(size_t)b * DM + coli] = f2bf(h);
                }
            }
            #pragma unroll
            for (int g = 0; g < 4; ++g) {
                size_t gfi = ((((size_t)bx * 128 + g * 32 + T) * 2 + mt) * 64 + lane) * 4;
                *(ushort4*)(g0o + gfi) = pk[g];
            }
            Cf[cfi] = cn4;
        } else {
            float si = sgW[coli], sf = sgW[coli + 512];
            float sgg = sgW[coli + 1024], so = sgW[coli + 1536];
            ushort4 gld[4];
            #pragma unroll
            for (int g = 0; g < 4; ++g) {
                size_t gfi = ((((size_t)bx * 128 + g * 32 + T) * 2 + mt) * 64 + lane) * 4;
                gld[g] = *(const ushort4*)(g0i + gfi);
            }
            float4 cold = Cf[cfi];
            float4 cn4;
            #pragma unroll
            for (int r = 0; r < 4; ++r) {
                float gi_ = acc[mt][0][r] + si  + bf2f(((unsigned short*)&gld[0])[r]);
                float gf_ = acc[mt][1][r] + sf  + bf2f(((unsigned short*)&gld[1])[r]);
                float gg_ = acc[mt][2][r] + sgg + bf2f(((unsigned short*)&gld[2])[r]);
                float go_ = acc[mt][3][r] + so  + bf2f(((unsigned short*)&gld[3])[r]);
                float cn = sigf(gf_) * (&cold.x)[r] + sigf(gi_) * tanhfast(gg_);
                (&cn4.x)[r] = cn;
                if (T < 16) {
                    int b = b0 + mt * 16 + quad * 4 + r;
                    float h = qv[(size_t)b * DM + coli] + sigf(go_) * tanhfast(cn);
                    if (mode == 1) hqo[(size_t)b * DM + coli] = f2bf(h);
                    else           preg[mt][r] += h * sg[coli];
                }
            }
            if (mode == 1) Cf[cfi] = cn4;
        }
    }

    if (mode == 2) {
        #pragma unroll
        for (int mt = 0; mt < 2; ++mt)
            #pragma unroll
            for (int r = 0; r < 4; ++r) {
                float p = preg[mt][r];
                p += __shfl_xor(p, 1, 64);
                p += __shfl_xor(p, 2, 64);
                p += __shfl_xor(p, 4, 64);
                p += __shfl_xor(p, 8, 64);
                if (nl == 0)
                    atomicAdd(out + b0 + mt * 16 + quad * 4 + r, p);
            }
    }
}

// ---------------------------------------------------------------------------
extern "C" void kernel_launch(void* const* d_in, const int* in_sizes, int n_in,
                              void* d_out, int out_size, void* d_ws, size_t ws_size,
                              hipStream_t stream) {
    const int* query   = (const int*)d_in[0];
    const int* support = (const int*)d_in[1];
    const int* q_l1 = (const int*)d_in[2];
    const int* q_l2 = (const int*)d_in[3];
    const int* q_r1 = (const int*)d_in[5];
    const int* q_r2 = (const int*)d_in[6];
    const int* s_l1 = (const int*)d_in[8];
    const int* s_l2 = (const int*)d_in[9];
    const int* s_r1 = (const int*)d_in[11];
    const int* s_r2 = (const int*)d_in[12];
    const float* emb    = (const float*)d_in[14];
    const float* gcn_W  = (const float*)d_in[15];
    const float* gcn_lb = (const float*)d_in[16];
    const float* gcn_b  = (const float*)d_in[17];
    const float* attn_W = (const float*)d_in[18];
    const float* attn_b = (const float*)d_in[19];
    const float* gate_W = (const float*)d_in[20];
    const float* gate_lb = (const float*)d_in[21];
    const float* gate_b  = (const float*)d_in[22];
    const float* p1_W = (const float*)d_in[23];
    const float* p1_b = (const float*)d_in[24];
    const float* p2_W = (const float*)d_in[25];
    const float* p2_b = (const float*)d_in[26];
    const float* ln_a = (const float*)d_in[27];
    const float* ln_b = (const float*)d_in[28];
    const float* Wih  = (const float*)d_in[29];
    const float* Whh  = (const float*)d_in[30];
    const float* bih  = (const float*)d_in[31];
    const float* bhh  = (const float*)d_in[32];

    // workspace layout: bf16 buffers first, then fp32 (16B-aligned blocks)
    unsigned short* P1   = (unsigned short*)d_ws;               // (V+1)*128
    unsigned short* P2   = P1 + (size_t)(VSZ + 1) * D;
    unsigned short* Wb   = P2 + (size_t)(VSZ + 1) * D;          // 256*128
    unsigned short* Wihp = Wb + 256 * 128;                      // 65536*8
    unsigned short* Whhp = Wihp + (size_t)65536 * 8;            // 65536*8
    unsigned short* g0b  = Whhp + (size_t)65536 * 8;            // NB*2048 (frag)
    unsigned short* hqA  = g0b + (size_t)NB * G4;               // NB*256
    unsigned short* hqB  = hqA + (size_t)NB * DM;               // NB*256
    unsigned short* qvbf = hqB + (size_t)NB * DM;               // NB*256
    float* fws = (float*)(qvbf + (size_t)NB * DM);
    float* gbv = fws;  fws += G4;
    float* qvb = fws;  fws += (size_t)NB * DM;                  // 4 MB
    float* svb = fws;  fws += DM;
    float* sgb = fws;  fws += DM;
    float* sgW = fws;  fws += G4 + 4;   // keep next block 16B-aligned
    float4* Cf = (float4*)fws;  fws += (size_t)NB * HSZ;        // 8 MB (frag)
    (void)in_sizes; (void)n_in; (void)out_size; (void)ws_size;

    k_wconv<<<128, 256, 0, stream>>>(gcn_W, Wb);
    k_pack<<<(131072 + 2048) / 256, 256, 0, stream>>>(
        Wih, Whh, bih, bhh, Wihp, Whhp, gbv);
    k_proj_mfma<<<(VSZ + 1 + 63) / 64, 256, 0, stream>>>(
        emb, Wb, gcn_lb, gcn_b, P1, P2, VSZ + 1);
    k_nbr<<<2 * (NB + 1), 256, 0, stream>>>(
        query, support, q_l1, q_l2, q_r1, q_r2, s_l1, s_l2, s_r1, s_r2,
        P1, P2, emb, attn_W, attn_b, gate_W, gate_lb, gate_b, qvb, qvbf, svb);
    k_sg<<<1, 256, 0, stream>>>(svb, p1_W, p1_b, p2_W, p2_b, ln_a, ln_b, sgb);
    k_sgwhh<<<G4 / 256, 256, 0, stream>>>(sgb, Whh, sgW);
    // step 1 (h_r = 0): A = qv bf16, B = Wih; write hqA
    k_lstm<<<dim3(NB / 32, 8), 256, 0, stream>>>(
        qvb, qvbf, Wihp, gbv, sgW, g0b, g0b, Cf, hqA, sgb, (float*)d_out, 0);
    // step 2: read hqA, write hqB
    k_lstm<<<dim3(NB / 32, 8), 256, 0, stream>>>(
        qvb, hqA, Whhp, gbv, sgW, g0b, g0b, Cf, hqB, sgb, (float*)d_out, 1);
    // step 3: read hqB, write hqA
    k_lstm<<<dim3(NB / 32, 8), 256, 0, stream>>>(
        qvb, hqB, Whhp, gbv, sgW, g0b, g0b, Cf, hqA, sgb, (float*)d_out, 1);
    // step 4: read hqA; only cols < 256 matter -> y < 4; atomic dot into out
    k_zero<<<NB / 256, 256, 0, stream>>>((float*)d_out);
    k_lstm<<<dim3(NB / 32, 4), 256, 0, stream>>>(
        qvb, hqA, Whhp, gbv, sgW, g0b, g0b, Cf, hqB, sgb, (float*)d_out, 2);
}